// Round 7
// baseline (206.717 us; speedup 1.0000x reference)
//
#include <hip/hip_runtime.h>

typedef __bf16 bf8 __attribute__((ext_vector_type(8)));
typedef float f4 __attribute__((ext_vector_type(4)));
typedef _Float16 h8 __attribute__((ext_vector_type(8)));

// Problem constants (fixed by reference)
constexpr int BSZ = 2, NSEQ = 2048, DIM = 512, NH = 8, DH = 64, INNER = 512;
constexpr int ROWS = BSZ * NSEQ;          // 4096

// Workspace layout (bytes)
constexpr size_t XB_OFF  = 0;                          // x cast bf16: 4096*512*2 = 4 MB
constexpr size_t WQT_OFF = 4194304;                    // W_qkv^T bf16 [1536][512] = 1.5 MB
constexpr size_t WOT_OFF = WQT_OFF + 1572864;          // W_out^T bf16 [512][512] = 0.5 MB
constexpr size_t Q_OFF   = WOT_OFF + 524288;           // Q/8 bf16 [2][8][2048][64] = 4 MB
constexpr size_t K_OFF   = Q_OFF + 4194304;            // K bf16 = 4 MB
constexpr size_t V_OFF   = K_OFF + 4194304;            // V bf16 = 4 MB
constexpr size_t AO_OFF  = V_OFF + 4194304;            // attn out bf16 [4096][512] = 4 MB

// ---------------- prep: cast x to bf16; transpose+cast W_qkv, W_out ----------------
__global__ __launch_bounds__(256) void prep_kernel(
    const float* __restrict__ x, const float* __restrict__ Wq, const float* __restrict__ Wo,
    __bf16* __restrict__ xb, __bf16* __restrict__ wqt, __bf16* __restrict__ wot) {
  int idx = blockIdx.x * 256 + threadIdx.x;
  if (idx < ROWS * DIM) xb[idx] = (__bf16)x[idx];
  if (idx < 3 * INNER * DIM) {            // wqt[n][k] = Wq[k][n],  n<1536, k<512
    int n = idx >> 9, k = idx & 511;
    wqt[idx] = (__bf16)Wq[k * (3 * INNER) + n];
  }
  if (idx < INNER * DIM) {                // wot[n][k] = Wo[k][n]
    int n = idx >> 9, k = idx & 511;
    wot[idx] = (__bf16)Wo[k * DIM + n];
  }
}

// ---------------- kernel 1: qkv = x @ W_qkv, scatter into per-head Q/8, K, V ----------------
__global__ __launch_bounds__(256) void qkv_gemm(
    const __bf16* __restrict__ xb, const __bf16* __restrict__ wqt,
    __bf16* __restrict__ Qh, __bf16* __restrict__ Kh, __bf16* __restrict__ Vh) {
  int bid = blockIdx.x;
  int bn = bid % 24, bm = bid / 24;           // 24 col-tiles of 64, 64 row-tiles of 64
  int lane = threadIdx.x & 63, wid = threadIdx.x >> 6;
  int r0 = bm * 64 + wid * 16;
  const __bf16* ap = xb  + (size_t)(r0 + (lane & 15)) * 512 + ((lane >> 4) * 8);
  const __bf16* bp = wqt + (size_t)(bn * 64 + (lane & 15)) * 512 + ((lane >> 4) * 8);
  f4 acc[4] = {{0.f,0.f,0.f,0.f},{0.f,0.f,0.f,0.f},{0.f,0.f,0.f,0.f},{0.f,0.f,0.f,0.f}};
#pragma unroll
  for (int kk = 0; kk < 16; ++kk) {
    bf8 a = *(const bf8*)(ap + kk * 32);
#pragma unroll
    for (int jt = 0; jt < 4; ++jt) {
      bf8 b = *(const bf8*)(bp + jt * 16 * 512 + kk * 32);
      acc[jt] = __builtin_amdgcn_mfma_f32_16x16x32_bf16(a, b, acc[jt], 0, 0, 0);
    }
  }
#pragma unroll
  for (int jt = 0; jt < 4; ++jt) {
    int col = bn * 64 + jt * 16 + (lane & 15);
    int which = col >> 9;                    // 0=q 1=k 2=v
    int inner = col & 511;
    int h = inner >> 6, d = inner & 63;
    __bf16* dst = which == 0 ? Qh : (which == 1 ? Kh : Vh);
    float scale = which == 0 ? 0.125f : 1.0f;  // fold SCALE=1/8 into Q (exact)
#pragma unroll
    for (int i = 0; i < 4; ++i) {
      int row = r0 + (lane >> 4) * 4 + i;
      int b = row >> 11, n = row & 2047;
      dst[(((size_t)(b * 8 + h)) * 2048 + n) * 64 + d] = (__bf16)(acc[jt][i] * scale);
    }
  }
}

// ---------------- kernel 2: sparsemax attention, 16 q-rows per workgroup ----------------
// f16 scores (64KB) + cand lists + rowmax -> ~73KB LDS -> 2 blocks/CU (8 waves/SIMD).
__global__ __launch_bounds__(1024, 8) void attn_kernel(
    const __bf16* __restrict__ Qh, const __bf16* __restrict__ Kh,
    const __bf16* __restrict__ Vh, __bf16* __restrict__ AO) {
  __shared__ _Float16 S[16 * 2048];         // 64 KB, XOR-swizzled (col ^= (row&12)<<2)
  __shared__ float candv[16][64];           // 4 KB
  __shared__ int   candj[16][64];           // 4 KB
  __shared__ float wrm[16][16];             // 1 KB: per-row per-wave partial max
  int bid = blockIdx.x;
  int lin = (bid & 7) * 256 + (bid >> 3);   // XCD-aware swizzle (2048 % 8 == 0, bijective)
  int bh = lin >> 7;                        // 0..15 = b*8+h
  int qt = lin & 127;                       // q-tile within head
  int lane = threadIdx.x & 63, wid = threadIdx.x >> 6;   // 16 waves
  int n0 = qt * 16;
  const __bf16* Qp = Qh + ((size_t)bh * 2048 + n0) * 64;
  const __bf16* Kp = Kh + (size_t)bh * 2048 * 64;
  const __bf16* Vp = Vh + (size_t)bh * 2048 * 64;
  int koff = (lane >> 4) * 8;
  int l15 = lane & 15, lg = lane >> 4;

  // ---- phase 1: S[16][2048] = (Q/8) @ K^T, f16 into LDS; row-max tracked in regs ----
  bf8 a0 = *(const bf8*)(Qp + l15 * 64 + koff);
  bf8 a1 = *(const bf8*)(Qp + l15 * 64 + 32 + koff);
  float m0 = -1e30f, m1 = -1e30f, m2 = -1e30f, m3 = -1e30f;
  const __bf16* kb0 = Kp + (size_t)(wid * 128 + l15) * 64 + koff;
  bf8 b0 = *(const bf8*)(kb0);
  bf8 b1 = *(const bf8*)(kb0 + 32);
#pragma unroll
  for (int t = 0; t < 8; ++t) {
    bf8 nb0, nb1;
    if (t < 7) {                            // prefetch next K-tile into regs
      const __bf16* kb = kb0 + (t + 1) * 16 * 64;
      nb0 = *(const bf8*)(kb);
      nb1 = *(const bf8*)(kb + 32);
    }
    f4 acc = {0.f, 0.f, 0.f, 0.f};
    acc = __builtin_amdgcn_mfma_f32_16x16x32_bf16(a0, b0, acc, 0, 0, 0);
    acc = __builtin_amdgcn_mfma_f32_16x16x32_bf16(a1, b1, acc, 0, 0, 0);
    int col = (wid * 8 + t) * 16 + l15;     // C layout: col=lane&15, row=lg*4+i
#pragma unroll
    for (int i = 0; i < 4; ++i) {
      int row = lg * 4 + i;
      S[row * 2048 + (col ^ ((row & 12) << 2))] = (_Float16)acc[i];
    }
    m0 = fmaxf(m0, acc[0]); m1 = fmaxf(m1, acc[1]);
    m2 = fmaxf(m2, acc[2]); m3 = fmaxf(m3, acc[3]);
    b0 = nb0; b1 = nb1;
  }
  // reduce row-max across the 16 lanes sharing lg (cols) — 4 steps
#pragma unroll
  for (int o = 1; o < 16; o <<= 1) {
    m0 = fmaxf(m0, __shfl_xor(m0, o)); m1 = fmaxf(m1, __shfl_xor(m1, o));
    m2 = fmaxf(m2, __shfl_xor(m2, o)); m3 = fmaxf(m3, __shfl_xor(m3, o));
  }
  if (l15 == 0) {
    wrm[lg * 4 + 0][wid] = m0; wrm[lg * 4 + 1][wid] = m1;
    wrm[lg * 4 + 2][wid] = m2; wrm[lg * 4 + 3][wid] = m3;
  }
  __syncthreads();

  // ---- phase 2: one wave per q-row ----
  int row = wid;
  int swz = (row & 12) << 2;
  const _Float16* Srow = S + row * 2048;

  // global row max: 16 broadcast LDS reads, serial fmax, identical in all lanes
  float gmx = -1e30f;
#pragma unroll
  for (int w = 0; w < 4; ++w) {
    f4 v = *(const f4*)&wrm[row][w * 4];
    gmx = fmaxf(fmaxf(fmaxf(gmx, v[0]), fmaxf(v[1], v[2])), v[3]);
  }
  float tau0 = gmx - 1.0f;                  // tau* >= max-1: z<=max-1 not in support

  h8 zc[4];
#pragma unroll
  for (int r = 0; r < 4; ++r)
    zc[r] = *(const h8*)&Srow[(r * 512 + lane * 8) ^ swz];

  unsigned mask = 0;
#pragma unroll
  for (int r = 0; r < 4; ++r)
#pragma unroll
    for (int i = 0; i < 8; ++i)
      if ((float)zc[r][i] > tau0) mask |= 1u << (r * 8 + i);
  int pc = __popc(mask);
  int off = pc;                             // inclusive prefix-scan over 64 lanes
#pragma unroll
  for (int d = 1; d < 64; d <<= 1) {
    int t = __shfl_up(off, d);
    if (lane >= d) off += t;
  }
  int total = __shfl(off, 63);              // candidates in this row (wave-uniform)
  off -= pc;                                // exclusive

  float tau = tau0, acc_o = 0.f;
  if (total <= 64) {
    // compact candidates to LDS (wave-private row)
    int slot = off;
#pragma unroll
    for (int r = 0; r < 4; ++r)
#pragma unroll
      for (int i = 0; i < 8; ++i)
        if (mask & (1u << (r * 8 + i))) {
          candv[row][slot] = (float)zc[r][i];
          candj[row][slot] = r * 512 + lane * 8 + i;
          ++slot;
        }
    // Michelot, shuffle-free: every lane walks the list redundantly (broadcast reads)
    float cprev = -1.0f;
    for (int it = 0; it < 24; ++it) {
      float s = 0.f, c = 0.f;
      for (int j = 0; j < total; ++j) {
        float v = candv[row][j];
        if (v > tau) { s += v; c += 1.f; }
      }
      if (c == cprev) break;
      tau = (s - 1.0f) / c; cprev = c;
    }
    // uniform gather over compact list: lane = output d, LDS broadcast of (p, j)
    for (int j = 0; j < total; ++j) {
      float p = candv[row][j] - tau;
      if (p > 0.f) {                        // wave-uniform branch
        int idx = candj[row][j];
        acc_o += p * (float)Vp[(size_t)idx * 64 + lane];
      }
    }
  } else {
    // fallback (rare): full-register Michelot from tau0 + ballot gather
    float cprev = -1.0f;
    for (int it = 0; it < 48; ++it) {
      float s = 0.f, c = 0.f;
#pragma unroll
      for (int r = 0; r < 4; ++r)
#pragma unroll
        for (int i = 0; i < 8; ++i) {
          float zz = (float)zc[r][i];
          if (zz > tau) { s += zz; c += 1.f; }
        }
#pragma unroll
      for (int o = 32; o; o >>= 1) { s += __shfl_xor(s, o); c += __shfl_xor(c, o); }
      if (c == cprev) break;
      tau = (s - 1.0f) / c; cprev = c;
    }
#pragma unroll
    for (int r = 0; r < 4; ++r)
#pragma unroll
      for (int i = 0; i < 8; ++i) {
        float p = (float)zc[r][i] - tau;
        unsigned long long m = __ballot(p > 0.f);
        while (m) {
          int src = __ffsll((long long)m) - 1;
          m &= m - 1;
          float pj = __shfl(p, src);
          int j = r * 512 + src * 8 + i;
          acc_o += pj * (float)Vp[(size_t)j * 64 + lane];
        }
      }
  }
  int rowg = (bh >> 3) * 2048 + n0 + row;   // [B][N] row
  AO[(size_t)rowg * 512 + (bh & 7) * 64 + lane] = (__bf16)acc_o;
}

// ---------------- kernel 3: out = AO @ W_out + b_out (f32 result) ----------------
__global__ __launch_bounds__(256) void out_gemm(
    const __bf16* __restrict__ A, const __bf16* __restrict__ wot,
    const float* __restrict__ bias, float* __restrict__ out) {
  int bid = blockIdx.x;
  int bn = bid & 7, bm = bid >> 3;          // 8 col-tiles of 64, 64 row-tiles
  int lane = threadIdx.x & 63, wid = threadIdx.x >> 6;
  int r0 = bm * 64 + wid * 16;
  const __bf16* ap = A   + (size_t)(r0 + (lane & 15)) * 512 + ((lane >> 4) * 8);
  const __bf16* bp = wot + (size_t)(bn * 64 + (lane & 15)) * 512 + ((lane >> 4) * 8);
  f4 acc[4] = {{0.f,0.f,0.f,0.f},{0.f,0.f,0.f,0.f},{0.f,0.f,0.f,0.f},{0.f,0.f,0.f,0.f}};
#pragma unroll
  for (int kk = 0; kk < 16; ++kk) {
    bf8 a = *(const bf8*)(ap + kk * 32);
#pragma unroll
    for (int jt = 0; jt < 4; ++jt) {
      bf8 b = *(const bf8*)(bp + jt * 16 * 512 + kk * 32);
      acc[jt] = __builtin_amdgcn_mfma_f32_16x16x32_bf16(a, b, acc[jt], 0, 0, 0);
    }
  }
#pragma unroll
  for (int jt = 0; jt < 4; ++jt) {
    int col = bn * 64 + jt * 16 + (lane & 15);
    float bv = bias[col];
#pragma unroll
    for (int i = 0; i < 4; ++i) {
      int row = r0 + (lane >> 4) * 4 + i;
      out[(size_t)row * 512 + col] = acc[jt][i] + bv;
    }
  }
}

extern "C" void kernel_launch(void* const* d_in, const int* in_sizes, int n_in,
                              void* d_out, int out_size, void* d_ws, size_t ws_size,
                              hipStream_t stream) {
  const float* x  = (const float*)d_in[0];
  const float* Wq = (const float*)d_in[1];
  const float* Wo = (const float*)d_in[2];
  const float* bo = (const float*)d_in[3];
  char* ws = (char*)d_ws;
  __bf16* xb  = (__bf16*)(ws + XB_OFF);
  __bf16* wqt = (__bf16*)(ws + WQT_OFF);
  __bf16* wot = (__bf16*)(ws + WOT_OFF);
  __bf16* Qh  = (__bf16*)(ws + Q_OFF);
  __bf16* Kh  = (__bf16*)(ws + K_OFF);
  __bf16* Vh  = (__bf16*)(ws + V_OFF);
  __bf16* AO  = (__bf16*)(ws + AO_OFF);

  prep_kernel<<<(ROWS * DIM) / 256, 256, 0, stream>>>(x, Wq, Wo, xb, wqt, wot);
  qkv_gemm<<<(ROWS / 64) * (3 * INNER / 64), 256, 0, stream>>>(xb, wqt, Qh, Kh, Vh);
  attn_kernel<<<16 * (NSEQ / 16), 1024, 0, stream>>>(Qh, Kh, Vh, AO);
  out_gemm<<<(ROWS / 64) * (INNER / 64), 256, 0, stream>>>(AO, wot, bo, (float*)d_out);
}

// Round 8
// 186.102 us; speedup vs baseline: 1.1108x; 1.1108x over previous
//
#include <hip/hip_runtime.h>

typedef __bf16 bf8 __attribute__((ext_vector_type(8)));
typedef float f4 __attribute__((ext_vector_type(4)));
typedef _Float16 h8 __attribute__((ext_vector_type(8)));

// Problem constants (fixed by reference)
constexpr int BSZ = 2, NSEQ = 2048, DIM = 512, NH = 8, DH = 64, INNER = 512;
constexpr int ROWS = BSZ * NSEQ;          // 4096

// Workspace layout (bytes)
constexpr size_t XB_OFF  = 0;                          // x cast bf16: 4096*512*2 = 4 MB
constexpr size_t WQT_OFF = 4194304;                    // W_qkv^T bf16 [1536][512] = 1.5 MB
constexpr size_t WOT_OFF = WQT_OFF + 1572864;          // W_out^T bf16 [512][512] = 0.5 MB
constexpr size_t Q_OFF   = WOT_OFF + 524288;           // Q/8 bf16 [2][8][2048][64] = 4 MB
constexpr size_t K_OFF   = Q_OFF + 4194304;            // K bf16 = 4 MB
constexpr size_t V_OFF   = K_OFF + 4194304;            // V bf16 = 4 MB
constexpr size_t AO_OFF  = V_OFF + 4194304;            // attn out bf16 [4096][512] = 4 MB

// ---------------- prep: cast x to bf16; transpose+cast W_qkv, W_out ----------------
__global__ __launch_bounds__(256) void prep_kernel(
    const float* __restrict__ x, const float* __restrict__ Wq, const float* __restrict__ Wo,
    __bf16* __restrict__ xb, __bf16* __restrict__ wqt, __bf16* __restrict__ wot) {
  int idx = blockIdx.x * 256 + threadIdx.x;
  if (idx < ROWS * DIM) xb[idx] = (__bf16)x[idx];
  if (idx < 3 * INNER * DIM) {            // wqt[n][k] = Wq[k][n],  n<1536, k<512
    int n = idx >> 9, k = idx & 511;
    wqt[idx] = (__bf16)Wq[k * (3 * INNER) + n];
  }
  if (idx < INNER * DIM) {                // wot[n][k] = Wo[k][n]
    int n = idx >> 9, k = idx & 511;
    wot[idx] = (__bf16)Wo[k * DIM + n];
  }
}

// ---------------- kernel 1: qkv = x @ W_qkv, scatter into per-head Q/8, K, V ----------------
__global__ __launch_bounds__(256) void qkv_gemm(
    const __bf16* __restrict__ xb, const __bf16* __restrict__ wqt,
    __bf16* __restrict__ Qh, __bf16* __restrict__ Kh, __bf16* __restrict__ Vh) {
  int bid = blockIdx.x;
  int bn = bid % 24, bm = bid / 24;           // 24 col-tiles of 64, 64 row-tiles of 64
  int lane = threadIdx.x & 63, wid = threadIdx.x >> 6;
  int r0 = bm * 64 + wid * 16;
  const __bf16* ap = xb  + (size_t)(r0 + (lane & 15)) * 512 + ((lane >> 4) * 8);
  const __bf16* bp = wqt + (size_t)(bn * 64 + (lane & 15)) * 512 + ((lane >> 4) * 8);
  f4 acc[4] = {{0.f,0.f,0.f,0.f},{0.f,0.f,0.f,0.f},{0.f,0.f,0.f,0.f},{0.f,0.f,0.f,0.f}};
#pragma unroll
  for (int kk = 0; kk < 16; ++kk) {
    bf8 a = *(const bf8*)(ap + kk * 32);
#pragma unroll
    for (int jt = 0; jt < 4; ++jt) {
      bf8 b = *(const bf8*)(bp + jt * 16 * 512 + kk * 32);
      acc[jt] = __builtin_amdgcn_mfma_f32_16x16x32_bf16(a, b, acc[jt], 0, 0, 0);
    }
  }
#pragma unroll
  for (int jt = 0; jt < 4; ++jt) {
    int col = bn * 64 + jt * 16 + (lane & 15);
    int which = col >> 9;                    // 0=q 1=k 2=v
    int inner = col & 511;
    int h = inner >> 6, d = inner & 63;
    __bf16* dst = which == 0 ? Qh : (which == 1 ? Kh : Vh);
    float scale = which == 0 ? 0.125f : 1.0f;  // fold SCALE=1/8 into Q (exact)
#pragma unroll
    for (int i = 0; i < 4; ++i) {
      int row = r0 + (lane >> 4) * 4 + i;
      int b = row >> 11, n = row & 2047;
      dst[(((size_t)(b * 8 + h)) * 2048 + n) * 64 + d] = (__bf16)(acc[jt][i] * scale);
    }
  }
}

// ---------------- kernel 2: sparsemax attention, 16 q-rows per workgroup ----------------
// f16 scores (64KB) + 8KB cand lists -> 72KB LDS -> 2 blocks/CU (full 8 waves/SIMD).
__global__ __launch_bounds__(1024, 8) void attn_kernel(
    const __bf16* __restrict__ Qh, const __bf16* __restrict__ Kh,
    const __bf16* __restrict__ Vh, __bf16* __restrict__ AO) {
  __shared__ _Float16 S[16 * 2048];         // 64 KB, XOR-swizzled (col ^= (row&12)<<2)
  __shared__ float candv[16][64];           // 4 KB
  __shared__ int   candj[16][64];           // 4 KB
  int bid = blockIdx.x;
  int lin = (bid & 7) * 256 + (bid >> 3);   // XCD-aware swizzle (2048 % 8 == 0, bijective)
  int bh = lin >> 7;                        // 0..15 = b*8+h
  int qt = lin & 127;                       // q-tile within head
  int lane = threadIdx.x & 63, wid = threadIdx.x >> 6;   // 16 waves
  int n0 = qt * 16;
  const __bf16* Qp = Qh + ((size_t)bh * 2048 + n0) * 64;
  const __bf16* Kp = Kh + (size_t)bh * 2048 * 64;
  const __bf16* Vp = Vh + (size_t)bh * 2048 * 64;
  int koff = (lane >> 4) * 8;

  // ---- phase 1: S[16][2048] = (Q/8) @ K^T, f16 into LDS ----
  bf8 a0 = *(const bf8*)(Qp + (lane & 15) * 64 + koff);
  bf8 a1 = *(const bf8*)(Qp + (lane & 15) * 64 + 32 + koff);
#pragma unroll
  for (int t = 0; t < 8; ++t) {
    int jt = wid * 8 + t;                   // 128 col-tiles over 16 waves
    const __bf16* kb = Kp + (size_t)(jt * 16 + (lane & 15)) * 64 + koff;
    bf8 b0 = *(const bf8*)(kb);
    bf8 b1 = *(const bf8*)(kb + 32);
    f4 acc = {0.f, 0.f, 0.f, 0.f};
    acc = __builtin_amdgcn_mfma_f32_16x16x32_bf16(a0, b0, acc, 0, 0, 0);
    acc = __builtin_amdgcn_mfma_f32_16x16x32_bf16(a1, b1, acc, 0, 0, 0);
#pragma unroll
    for (int i = 0; i < 4; ++i) {
      int row = (lane >> 4) * 4 + i;        // C layout: col=lane&15, row=(lane>>4)*4+i
      int col = jt * 16 + (lane & 15);
      S[row * 2048 + (col ^ ((row & 12) << 2))] = (_Float16)acc[i];
    }
  }
  __syncthreads();

  // ---- phase 2: one wave per q-row ----
  int row = wid;
  int swz = (row & 12) << 2;
  const _Float16* Srow = S + row * 2048;
  h8 zc[4];
#pragma unroll
  for (int r = 0; r < 4; ++r)
    zc[r] = *(const h8*)&Srow[(r * 512 + lane * 8) ^ swz];

  // row max (butterfly leaves identical value in all lanes)
  float mx = -1e30f;
#pragma unroll
  for (int r = 0; r < 4; ++r)
#pragma unroll
    for (int i = 0; i < 8; ++i) mx = fmaxf(mx, (float)zc[r][i]);
#pragma unroll
  for (int o = 32; o; o >>= 1) mx = fmaxf(mx, __shfl_xor(mx, o));

  // tau* >= max-1 (p_max <= 1), so z <= max-1 is provably outside the support.
  float tau0 = mx - 1.0f;
  // prefill this wave's cand row so unwritten slots are inert
  candv[row][lane] = -1e30f;
  candj[row][lane] = 0;
  unsigned mask = 0;
#pragma unroll
  for (int r = 0; r < 4; ++r)
#pragma unroll
    for (int i = 0; i < 8; ++i)
      if ((float)zc[r][i] > tau0) mask |= 1u << (r * 8 + i);
  int pc = __popc(mask);
  int off = pc;                             // inclusive prefix-scan over 64 lanes
#pragma unroll
  for (int d = 1; d < 64; d <<= 1) {
    int t = __shfl_up(off, d);
    if (lane >= d) off += t;
  }
  int total = __shfl(off, 63);              // candidates in this row (wave-uniform)
  off -= pc;                                // exclusive

  float tau = tau0, acc_o = 0.f;
  if (total <= 64) {
    // compact candidates to LDS (wave-private row; no barrier needed)
    int slot = off;
#pragma unroll
    for (int r = 0; r < 4; ++r)
#pragma unroll
      for (int i = 0; i < 8; ++i)
        if (mask & (1u << (r * 8 + i))) {
          candv[row][slot] = (float)zc[r][i];
          candj[row][slot] = r * 512 + lane * 8 + i;
          ++slot;
        }
    if (total <= 16) {
      // register path: 4 broadcast b128 loads, then pure-VALU Michelot (no cross-lane)
      f4 cv0 = *(const f4*)&candv[row][0];
      f4 cv1 = *(const f4*)&candv[row][4];
      f4 cv2 = *(const f4*)&candv[row][8];
      f4 cv3 = *(const f4*)&candv[row][12];
      float cprev = -1.0f;
      for (int it = 0; it < 20; ++it) {
        float s = 0.f, c = 0.f;
#pragma unroll
        for (int i = 0; i < 4; ++i) {
          if (cv0[i] > tau) { s += cv0[i]; c += 1.f; }
          if (cv1[i] > tau) { s += cv1[i]; c += 1.f; }
          if (cv2[i] > tau) { s += cv2[i]; c += 1.f; }
          if (cv3[i] > tau) { s += cv3[i]; c += 1.f; }
        }
        if (c == cprev) break;
        tau = (s - 1.0f) / c; cprev = c;
      }
      // branchless pipelined gather: dead slots have p<=0 -> contribute exactly 0
      const __bf16* vb = Vp + lane;
#pragma unroll
      for (int jc = 0; jc < 4; ++jc) {
        f4 cj = jc == 0 ? cv0 : (jc == 1 ? cv1 : (jc == 2 ? cv2 : cv3));
        int j0 = candj[row][jc * 4 + 0];
        int j1 = candj[row][jc * 4 + 1];
        int j2 = candj[row][jc * 4 + 2];
        int j3 = candj[row][jc * 4 + 3];
        acc_o += fmaxf(cj[0] - tau, 0.f) * (float)vb[(size_t)j0 * 64];
        acc_o += fmaxf(cj[1] - tau, 0.f) * (float)vb[(size_t)j1 * 64];
        acc_o += fmaxf(cj[2] - tau, 0.f) * (float)vb[(size_t)j2 * 64];
        acc_o += fmaxf(cj[3] - tau, 0.f) * (float)vb[(size_t)j3 * 64];
      }
    } else {
      // mid path: Michelot on 1 candidate per lane (butterfly reduce)
      float v = candv[row][lane];
      bool valid = lane < total;
      float cprev = -1.0f;
      for (int it = 0; it < 24; ++it) {
        bool in = valid && (v > tau);
        float s = in ? v : 0.f, c = in ? 1.f : 0.f;
#pragma unroll
        for (int o = 32; o; o >>= 1) { s += __shfl_xor(s, o); c += __shfl_xor(c, o); }
        if (c == cprev) break;
        tau = (s - 1.0f) / c; cprev = c;
      }
      for (int j = 0; j < total; ++j) {
        float p = candv[row][j] - tau;
        if (p > 0.f) {                      // wave-uniform branch
          int idx = candj[row][j];
          acc_o += p * (float)Vp[(size_t)idx * 64 + lane];
        }
      }
    }
  } else {
    // fallback (rare): full-register Michelot from tau0 + ballot gather
    float cprev = -1.0f;
    for (int it = 0; it < 48; ++it) {
      float s = 0.f, c = 0.f;
#pragma unroll
      for (int r = 0; r < 4; ++r)
#pragma unroll
        for (int i = 0; i < 8; ++i) {
          float zz = (float)zc[r][i];
          if (zz > tau) { s += zz; c += 1.f; }
        }
#pragma unroll
      for (int o = 32; o; o >>= 1) { s += __shfl_xor(s, o); c += __shfl_xor(c, o); }
      if (c == cprev) break;
      tau = (s - 1.0f) / c; cprev = c;
    }
#pragma unroll
    for (int r = 0; r < 4; ++r)
#pragma unroll
      for (int i = 0; i < 8; ++i) {
        float p = (float)zc[r][i] - tau;
        unsigned long long m = __ballot(p > 0.f);
        while (m) {
          int src = __ffsll((long long)m) - 1;
          m &= m - 1;
          float pj = __shfl(p, src);
          int j = r * 512 + src * 8 + i;
          acc_o += pj * (float)Vp[(size_t)j * 64 + lane];
        }
      }
  }
  int rowg = (bh >> 3) * 2048 + n0 + row;   // [B][N] row
  AO[(size_t)rowg * 512 + (bh & 7) * 64 + lane] = (__bf16)acc_o;
}

// ---------------- kernel 3: out = AO @ W_out + b_out (f32 result) ----------------
__global__ __launch_bounds__(256) void out_gemm(
    const __bf16* __restrict__ A, const __bf16* __restrict__ wot,
    const float* __restrict__ bias, float* __restrict__ out) {
  int bid = blockIdx.x;
  int bn = bid & 7, bm = bid >> 3;          // 8 col-tiles of 64, 64 row-tiles
  int lane = threadIdx.x & 63, wid = threadIdx.x >> 6;
  int r0 = bm * 64 + wid * 16;
  const __bf16* ap = A   + (size_t)(r0 + (lane & 15)) * 512 + ((lane >> 4) * 8);
  const __bf16* bp = wot + (size_t)(bn * 64 + (lane & 15)) * 512 + ((lane >> 4) * 8);
  f4 acc[4] = {{0.f,0.f,0.f,0.f},{0.f,0.f,0.f,0.f},{0.f,0.f,0.f,0.f},{0.f,0.f,0.f,0.f}};
#pragma unroll
  for (int kk = 0; kk < 16; ++kk) {
    bf8 a = *(const bf8*)(ap + kk * 32);
#pragma unroll
    for (int jt = 0; jt < 4; ++jt) {
      bf8 b = *(const bf8*)(bp + jt * 16 * 512 + kk * 32);
      acc[jt] = __builtin_amdgcn_mfma_f32_16x16x32_bf16(a, b, acc[jt], 0, 0, 0);
    }
  }
#pragma unroll
  for (int jt = 0; jt < 4; ++jt) {
    int col = bn * 64 + jt * 16 + (lane & 15);
    float bv = bias[col];
#pragma unroll
    for (int i = 0; i < 4; ++i) {
      int row = r0 + (lane >> 4) * 4 + i;
      out[(size_t)row * 512 + col] = acc[jt][i] + bv;
    }
  }
}

extern "C" void kernel_launch(void* const* d_in, const int* in_sizes, int n_in,
                              void* d_out, int out_size, void* d_ws, size_t ws_size,
                              hipStream_t stream) {
  const float* x  = (const float*)d_in[0];
  const float* Wq = (const float*)d_in[1];
  const float* Wo = (const float*)d_in[2];
  const float* bo = (const float*)d_in[3];
  char* ws = (char*)d_ws;
  __bf16* xb  = (__bf16*)(ws + XB_OFF);
  __bf16* wqt = (__bf16*)(ws + WQT_OFF);
  __bf16* wot = (__bf16*)(ws + WOT_OFF);
  __bf16* Qh  = (__bf16*)(ws + Q_OFF);
  __bf16* Kh  = (__bf16*)(ws + K_OFF);
  __bf16* Vh  = (__bf16*)(ws + V_OFF);
  __bf16* AO  = (__bf16*)(ws + AO_OFF);

  prep_kernel<<<(ROWS * DIM) / 256, 256, 0, stream>>>(x, Wq, Wo, xb, wqt, wot);
  qkv_gemm<<<(ROWS / 64) * (3 * INNER / 64), 256, 0, stream>>>(xb, wqt, Qh, Kh, Vh);
  attn_kernel<<<16 * (NSEQ / 16), 1024, 0, stream>>>(Qh, Kh, Vh, AO);
  out_gemm<<<(ROWS / 64) * (INNER / 64), 256, 0, stream>>>(AO, wot, bo, (float*)d_out);
}